// Round 1
// baseline (1046.603 us; speedup 1.0000x reference)
//
#include <hip/hip_runtime.h>

#define N_NODES 50000
#define DIM 64
#define EDGE_DIM 32
#define HEADS 8
#define EXP_HEADS 16
#define NEDGE 800000
#define SCALE 0.35355339059327373f  /* 8^-0.5 */
#define EPS 1e-16f

// monotone float->uint key for atomicMax-based float max
__device__ __forceinline__ unsigned fkey(float f) {
    unsigned b = __float_as_uint(f);
    return (b & 0x80000000u) ? ~b : (b | 0x80000000u);
}
__device__ __forceinline__ float fdecode(unsigned u) {
    unsigned b = (u & 0x80000000u) ? (u ^ 0x80000000u) : ~u;
    return __uint_as_float(b);
}

// ---- Kernel A: q,k,v = x @ {Wq,Wk,Wv} ------------------------------------
__global__ __launch_bounds__(256) void qkv_kernel(
    const float* __restrict__ x, const float* __restrict__ Wq,
    const float* __restrict__ Wk, const float* __restrict__ Wv,
    float* __restrict__ q, float* __restrict__ k, float* __restrict__ v) {
    int gid = blockIdx.x * 256 + threadIdx.x;
    if (gid >= N_NODES * DIM) return;
    int i = gid >> 6, j = gid & 63;
    const float* xr = x + i * DIM;
    float aq = 0.f, ak = 0.f, av = 0.f;
#pragma unroll
    for (int l = 0; l < DIM; ++l) {
        float xv = xr[l];
        aq = fmaf(xv, Wq[l * DIM + j], aq);
        ak = fmaf(xv, Wk[l * DIM + j], ak);
        av = fmaf(xv, Wv[l * DIM + j], av);
    }
    q[gid] = aq; k[gid] = ak; v[gid] = av;
}

// ---- Kernel B: per-edge attention logits + segment max --------------------
__global__ __launch_bounds__(256) void edge_attn_kernel(
    const float* __restrict__ edges, const int* __restrict__ eidx,
    const float* __restrict__ q, const float* __restrict__ k,
    const float* __restrict__ Wek, const float* __restrict__ Wexp,
    const float* __restrict__ temp,
    float* __restrict__ attn16, unsigned* __restrict__ mx) {
    __shared__ float sWek[EDGE_DIM * DIM];
    __shared__ float sWexp[HEADS * EXP_HEADS];
    __shared__ float sEdge[4][EDGE_DIM];
    int tid = threadIdx.x;
    for (int i = tid; i < EDGE_DIM * DIM; i += 256) sWek[i] = Wek[i];
    if (tid < HEADS * EXP_HEADS) sWexp[tid] = Wexp[tid];
    int w = tid >> 6, lane = tid & 63;
    int e = blockIdx.x * 4 + w;  // NEDGE % 4 == 0, grid exact
    if (lane < EDGE_DIM) sEdge[w][lane] = edges[(long)e * EDGE_DIM + lane];
    __syncthreads();
    int dst = eidx[e], src = eidx[NEDGE + e];
    // edge_k column `lane`
    float ek = 0.f;
#pragma unroll
    for (int l = 0; l < EDGE_DIM; ++l) ek = fmaf(sEdge[w][l], sWek[l * DIM + lane], ek);
    float qe = q[(long)dst * DIM + lane];
    float ke = (k[(long)src * DIM + lane] + ek) * SCALE;
    float p = qe * ke;
    // reduce within 8-lane head group
    p += __shfl_xor(p, 1);
    p += __shfl_xor(p, 2);
    p += __shfl_xor(p, 4);
    float s = p / temp[0];  // attn for head = lane>>3
    float sh[HEADS];
#pragma unroll
    for (int h = 0; h < HEADS; ++h) sh[h] = __shfl(s, h * 8);
    if (lane < EXP_HEADS) {
        float a = 0.f;
#pragma unroll
        for (int h = 0; h < HEADS; ++h) a = fmaf(sh[h], sWexp[h * EXP_HEADS + lane], a);
        attn16[(long)e * EXP_HEADS + lane] = a;
        atomicMax(&mx[dst * EXP_HEADS + lane], fkey(a));
    }
}

// ---- Kernel C: exp(a - mx) in place + segment sum -------------------------
__global__ __launch_bounds__(256) void softmax_pass2(
    float* __restrict__ attn16, const int* __restrict__ eidx,
    const unsigned* __restrict__ mx, float* __restrict__ sm) {
    long gid = (long)blockIdx.x * 256 + threadIdx.x;
    if (gid >= (long)NEDGE * EXP_HEADS) return;
    int e = (int)(gid >> 4), j = (int)(gid & 15);
    int dst = eidx[e];
    float m = fdecode(mx[dst * EXP_HEADS + j]);
    float ex = __expf(attn16[gid] - m);
    attn16[gid] = ex;
    atomicAdd(&sm[dst * EXP_HEADS + j], ex);
}

// ---- Kernel D: normalize, @Wsq+bsq, attn out, edge_v, scatter agg ---------
__global__ __launch_bounds__(256) void edge_out_kernel(
    const float* __restrict__ edges, const int* __restrict__ eidx,
    const float* __restrict__ v, const float* __restrict__ attn16,
    const float* __restrict__ sm,
    const float* __restrict__ Wev, const float* __restrict__ Wsq,
    const float* __restrict__ bsq,
    float* __restrict__ attn_out, float* __restrict__ agg) {
    __shared__ float sWev[EDGE_DIM * DIM];
    __shared__ float sWsq[EXP_HEADS * HEADS];
    __shared__ float sbsq[HEADS];
    __shared__ float sEdge[4][EDGE_DIM];
    int tid = threadIdx.x;
    for (int i = tid; i < EDGE_DIM * DIM; i += 256) sWev[i] = Wev[i];
    if (tid < EXP_HEADS * HEADS) sWsq[tid] = Wsq[tid];
    if (tid < HEADS) sbsq[tid] = bsq[tid];
    int w = tid >> 6, lane = tid & 63;
    int e = blockIdx.x * 4 + w;
    if (lane < EDGE_DIM) sEdge[w][lane] = edges[(long)e * EDGE_DIM + lane];
    __syncthreads();
    int dst = eidx[e], src = eidx[NEDGE + e];
    float a = 0.f;
    if (lane < EXP_HEADS) {
        float ex = attn16[(long)e * EXP_HEADS + lane];
        a = ex / (sm[dst * EXP_HEADS + lane] + EPS);
    }
    int h = lane >> 3;
    float a8 = sbsq[h];
#pragma unroll
    for (int j = 0; j < EXP_HEADS; ++j) a8 = fmaf(__shfl(a, j), sWsq[j * HEADS + h], a8);
    if ((lane & 7) == 0) attn_out[(long)h * NEDGE + e] = a8;  // attn.T [8,E]
    float ev = 0.f;
#pragma unroll
    for (int l = 0; l < EDGE_DIM; ++l) ev = fmaf(sEdge[w][l], sWev[l * DIM + lane], ev);
    float o = a8 * (v[(long)src * DIM + lane] + ev);
    atomicAdd(&agg[(long)dst * DIM + lane], o);
}

// ---- Kernel E: out = (v - agg) @ Wout + bout ------------------------------
__global__ __launch_bounds__(256) void out_kernel(
    const float* __restrict__ v, const float* __restrict__ agg,
    const float* __restrict__ Wout, const float* __restrict__ bout,
    float* __restrict__ out) {
    int gid = blockIdx.x * 256 + threadIdx.x;
    if (gid >= N_NODES * DIM) return;
    int i = gid >> 6, j = gid & 63;
    float acc = bout[j];
#pragma unroll
    for (int l = 0; l < DIM; ++l)
        acc = fmaf(v[i * DIM + l] - agg[i * DIM + l], Wout[l * DIM + j], acc);
    out[gid] = acc;
}

extern "C" void kernel_launch(void* const* d_in, const int* in_sizes, int n_in,
                              void* d_out, int out_size, void* d_ws, size_t ws_size,
                              hipStream_t stream) {
    const float* x     = (const float*)d_in[0];
    const float* edges = (const float*)d_in[1];
    const int*   eidx  = (const int*)d_in[2];
    const float* Wq    = (const float*)d_in[3];
    const float* Wk    = (const float*)d_in[4];
    const float* Wv    = (const float*)d_in[5];
    const float* Wek   = (const float*)d_in[6];
    const float* Wev   = (const float*)d_in[7];
    const float* Wexp  = (const float*)d_in[8];
    const float* Wsq   = (const float*)d_in[9];
    const float* bsq   = (const float*)d_in[10];
    const float* Wout  = (const float*)d_in[11];
    const float* bout  = (const float*)d_in[12];
    const float* temp  = (const float*)d_in[13];

    float* ws = (float*)d_ws;
    float* q      = ws;
    float* k      = q + (long)N_NODES * DIM;
    float* v      = k + (long)N_NODES * DIM;
    float* attn16 = v + (long)N_NODES * DIM;
    unsigned* mx  = (unsigned*)(attn16 + (long)NEDGE * EXP_HEADS);
    float* sm     = (float*)(mx + (long)N_NODES * EXP_HEADS);
    float* agg    = sm + (long)N_NODES * EXP_HEADS;

    // zero mx (uint key 0 == -inf identity), sm, agg — contiguous region
    size_t zbytes = ((size_t)N_NODES * EXP_HEADS * 2 + (size_t)N_NODES * DIM) * sizeof(float);
    hipMemsetAsync(mx, 0, zbytes, stream);

    float* out1 = (float*)d_out;                       // [N, 64]
    float* out2 = out1 + (long)N_NODES * DIM;          // [8, E]

    qkv_kernel<<<(N_NODES * DIM + 255) / 256, 256, 0, stream>>>(x, Wq, Wk, Wv, q, k, v);
    edge_attn_kernel<<<NEDGE / 4, 256, 0, stream>>>(edges, eidx, q, k, Wek, Wexp, temp, attn16, mx);
    softmax_pass2<<<(int)(((long)NEDGE * EXP_HEADS + 255) / 256), 256, 0, stream>>>(attn16, eidx, mx, sm);
    edge_out_kernel<<<NEDGE / 4, 256, 0, stream>>>(edges, eidx, v, attn16, sm, Wev, Wsq, bsq, out2, agg);
    out_kernel<<<(N_NODES * DIM + 255) / 256, 256, 0, stream>>>(v, agg, Wout, bout, out1);
}

// Round 2
// 993.510 us; speedup vs baseline: 1.0534x; 1.0534x over previous
//
#include <hip/hip_runtime.h>

#define N_NODES 50000
#define DIM 64
#define EDGE_DIM 32
#define HEADS 8
#define EXP_HEADS 16
#define NEDGE 800000
#define SCALE 0.35355339059327373f  /* 8^-0.5 */
#define EPS 1e-16f
#define NEG_BIG -1e30f

// ---- Kernel A: q,k,v = x @ {Wq,Wk,Wv} ------------------------------------
__global__ __launch_bounds__(256) void qkv_kernel(
    const float* __restrict__ x, const float* __restrict__ Wq,
    const float* __restrict__ Wk, const float* __restrict__ Wv,
    float* __restrict__ q, float* __restrict__ k, float* __restrict__ v) {
    int gid = blockIdx.x * 256 + threadIdx.x;
    if (gid >= N_NODES * DIM) return;
    int i = gid >> 6, j = gid & 63;
    const float* xr = x + i * DIM;
    float aq = 0.f, ak = 0.f, av = 0.f;
#pragma unroll
    for (int l = 0; l < DIM; ++l) {
        float xv = xr[l];
        aq = fmaf(xv, Wq[l * DIM + j], aq);
        ak = fmaf(xv, Wk[l * DIM + j], ak);
        av = fmaf(xv, Wv[l * DIM + j], av);
    }
    q[gid] = aq; k[gid] = ak; v[gid] = av;
}

// ---- CSR build: histogram --------------------------------------------------
__global__ __launch_bounds__(256) void hist_kernel(
    const int* __restrict__ eidx, unsigned* __restrict__ cnt) {
    int e = blockIdx.x * 256 + threadIdx.x;
    if (e >= NEDGE) return;
    atomicAdd(&cnt[eidx[e]], 1u);
}

// ---- CSR build: single-block exclusive scan over 50k counts ---------------
#define SCAN_T 1024
#define CHUNK 49  /* ceil(50000/1024) */
__global__ __launch_bounds__(SCAN_T) void scan_kernel(
    const unsigned* __restrict__ cnt, unsigned* __restrict__ offsets,
    unsigned* __restrict__ cursor) {
    __shared__ unsigned ps[SCAN_T];
    int t = threadIdx.x;
    int lo = t * CHUNK, hi = min(lo + CHUNK, N_NODES);
    unsigned loc = 0;
    for (int i = lo; i < hi; ++i) loc += cnt[i];
    ps[t] = loc;
    __syncthreads();
    for (int off = 1; off < SCAN_T; off <<= 1) {
        unsigned val = (t >= off) ? ps[t - off] : 0u;
        __syncthreads();
        ps[t] += val;
        __syncthreads();
    }
    unsigned run = ps[t] - loc;  // exclusive base for this chunk
    for (int i = lo; i < hi; ++i) {
        offsets[i] = run; cursor[i] = run; run += cnt[i];
    }
    if (t == SCAN_T - 1) offsets[N_NODES] = ps[SCAN_T - 1];
}

// ---- CSR build: scatter edge ids into sorted order -------------------------
__global__ __launch_bounds__(256) void scatter_kernel(
    const int* __restrict__ eidx, unsigned* __restrict__ cursor,
    unsigned* __restrict__ perm) {
    int e = blockIdx.x * 256 + threadIdx.x;
    if (e >= NEDGE) return;
    int dst = eidx[e];
    unsigned pos = atomicAdd(&cursor[dst], 1u);
    perm[pos] = e;
}

// ---- Kernel B: per-edge attention logits (no atomics) ----------------------
__global__ __launch_bounds__(256) void edge_attn_kernel(
    const float* __restrict__ edges, const int* __restrict__ eidx,
    const float* __restrict__ q, const float* __restrict__ k,
    const float* __restrict__ Wek, const float* __restrict__ Wexp,
    const float* __restrict__ temp, float* __restrict__ attn16) {
    __shared__ float sWek[EDGE_DIM * DIM];
    __shared__ float sWexp[HEADS * EXP_HEADS];
    __shared__ float sEdge[4][EDGE_DIM];
    int tid = threadIdx.x;
    for (int i = tid; i < EDGE_DIM * DIM; i += 256) sWek[i] = Wek[i];
    if (tid < HEADS * EXP_HEADS) sWexp[tid] = Wexp[tid];
    int w = tid >> 6, lane = tid & 63;
    int e = blockIdx.x * 4 + w;  // NEDGE % 4 == 0
    if (lane < EDGE_DIM) sEdge[w][lane] = edges[(long)e * EDGE_DIM + lane];
    __syncthreads();
    int dst = eidx[e], src = eidx[NEDGE + e];
    float ek = 0.f;
#pragma unroll
    for (int l = 0; l < EDGE_DIM; ++l) ek = fmaf(sEdge[w][l], sWek[l * DIM + lane], ek);
    float qe = q[(long)dst * DIM + lane];
    float ke = (k[(long)src * DIM + lane] + ek) * SCALE;
    float p = qe * ke;
    p += __shfl_xor(p, 1);
    p += __shfl_xor(p, 2);
    p += __shfl_xor(p, 4);
    float s = p / temp[0];
    float sh[HEADS];
#pragma unroll
    for (int h = 0; h < HEADS; ++h) sh[h] = __shfl(s, h * 8);
    if (lane < EXP_HEADS) {
        float a = 0.f;
#pragma unroll
        for (int h = 0; h < HEADS; ++h) a = fmaf(sh[h], sWexp[h * EXP_HEADS + lane], a);
        attn16[(long)e * EXP_HEADS + lane] = a;
    }
}

// ---- Kernel C: per-node segment softmax + Wsq + PV aggregation -------------
__global__ __launch_bounds__(256) void node_kernel(
    const float* __restrict__ edges, const int* __restrict__ eidx,
    const float* __restrict__ v, const float* __restrict__ attn16,
    const unsigned* __restrict__ offsets, const unsigned* __restrict__ perm,
    const float* __restrict__ Wev, const float* __restrict__ Wsq,
    const float* __restrict__ bsq,
    float* __restrict__ a8buf, float* __restrict__ vmagg) {
    __shared__ float sT[4][8][33];  // padded: conflict-free t staging
    int tid = threadIdx.x;
    int w = tid >> 6, lane = tid & 63;
    int n = blockIdx.x * 4 + w;  // N_NODES % 4 == 0
    int h = lane >> 3, d = lane & 7;
    float wsq[EXP_HEADS];
#pragma unroll
    for (int j = 0; j < EXP_HEADS; ++j) wsq[j] = Wsq[j * HEADS + h];
    float bsq_r = bsq[h];

    unsigned nb = offsets[n];
    int deg = (int)(offsets[n + 1] - nb);

    // online softmax over the segment, 4 edges per iteration (lane groups)
    float m = NEG_BIG, s = 0.f;
    int g = lane >> 4, eh = lane & 15;
    for (int j0 = 0; j0 < deg; j0 += 4) {
        int j = j0 + g;
        if (j < deg) {
            int e = (int)perm[nb + j];
            float a = attn16[(long)e * EXP_HEADS + eh];
            float mn = fmaxf(m, a);
            s = s * __expf(m - mn) + __expf(a - mn);
            m = mn;
        }
    }
#pragma unroll
    for (int off = 16; off < 64; off <<= 1) {
        float m2 = __shfl_xor(m, off), s2 = __shfl_xor(s, off);
        float mn = fmaxf(m, m2);
        s = s * __expf(m - mn) + s2 * __expf(m2 - mn);
        m = mn;
    }
    float rs = 1.f / (s + EPS);

    // PV: acc = sum a8*v[src]; t[h][l] = sum a8*edges[l]  (Wev factored out)
    float acc = 0.f, t0 = 0.f, t1 = 0.f, t2 = 0.f, t3 = 0.f;
    for (int j = 0; j < deg; ++j) {
        long sj = (long)nb + j;
        int e = (int)perm[sj];
        int src = eidx[NEDGE + e];
        float aval = attn16[(long)e * EXP_HEADS + eh];
        float a = __expf(aval - m) * rs;
        float a8 = bsq_r;
#pragma unroll
        for (int jj = 0; jj < EXP_HEADS; ++jj) a8 = fmaf(__shfl(a, jj), wsq[jj], a8);
        if (d == 0) a8buf[(long)e * HEADS + h] = a8;
        float erow = edges[(long)e * EDGE_DIM + (lane & 31)];
        float vv = v[(long)src * DIM + lane];
        acc = fmaf(a8, vv, acc);
        t0 = fmaf(a8, __shfl(erow, d * 4 + 0), t0);
        t1 = fmaf(a8, __shfl(erow, d * 4 + 1), t1);
        t2 = fmaf(a8, __shfl(erow, d * 4 + 2), t2);
        t3 = fmaf(a8, __shfl(erow, d * 4 + 3), t3);
    }
    sT[w][h][d * 4 + 0] = t0;
    sT[w][h][d * 4 + 1] = t1;
    sT[w][h][d * 4 + 2] = t2;
    sT[w][h][d * 4 + 3] = t3;
    __syncthreads();
    float ev = 0.f;
#pragma unroll
    for (int l = 0; l < EDGE_DIM; ++l) ev = fmaf(sT[w][h][l], Wev[l * DIM + lane], ev);
    vmagg[(long)n * DIM + lane] = v[(long)n * DIM + lane] - (acc + ev);
}

// ---- transpose a8buf [E,8] -> attn.T [8,E] ---------------------------------
__global__ __launch_bounds__(256) void transpose_kernel(
    const float* __restrict__ a8buf, float* __restrict__ out2) {
    int e = blockIdx.x * 256 + threadIdx.x;
    if (e >= NEDGE) return;
    const float4* p = (const float4*)(a8buf + (long)e * 8);
    float4 lo = p[0], hi = p[1];
    out2[0L * NEDGE + e] = lo.x; out2[1L * NEDGE + e] = lo.y;
    out2[2L * NEDGE + e] = lo.z; out2[3L * NEDGE + e] = lo.w;
    out2[4L * NEDGE + e] = hi.x; out2[5L * NEDGE + e] = hi.y;
    out2[6L * NEDGE + e] = hi.z; out2[7L * NEDGE + e] = hi.w;
}

// ---- Kernel E: out = vmagg @ Wout + bout -----------------------------------
__global__ __launch_bounds__(256) void out_kernel(
    const float* __restrict__ vmagg, const float* __restrict__ Wout,
    const float* __restrict__ bout, float* __restrict__ out) {
    int gid = blockIdx.x * 256 + threadIdx.x;
    if (gid >= N_NODES * DIM) return;
    int i = gid >> 6, j = gid & 63;
    float acc = bout[j];
#pragma unroll
    for (int l = 0; l < DIM; ++l)
        acc = fmaf(vmagg[i * DIM + l], Wout[l * DIM + j], acc);
    out[gid] = acc;
}

extern "C" void kernel_launch(void* const* d_in, const int* in_sizes, int n_in,
                              void* d_out, int out_size, void* d_ws, size_t ws_size,
                              hipStream_t stream) {
    const float* x     = (const float*)d_in[0];
    const float* edges = (const float*)d_in[1];
    const int*   eidx  = (const int*)d_in[2];
    const float* Wq    = (const float*)d_in[3];
    const float* Wk    = (const float*)d_in[4];
    const float* Wv    = (const float*)d_in[5];
    const float* Wek   = (const float*)d_in[6];
    const float* Wev   = (const float*)d_in[7];
    const float* Wexp  = (const float*)d_in[8];
    const float* Wsq   = (const float*)d_in[9];
    const float* bsq   = (const float*)d_in[10];
    const float* Wout  = (const float*)d_in[11];
    const float* bout  = (const float*)d_in[12];
    const float* temp  = (const float*)d_in[13];

    float* ws = (float*)d_ws;
    float* q      = ws;                             // 3.2M floats
    float* k      = q + (long)N_NODES * DIM;        // 3.2M
    float* v      = k + (long)N_NODES * DIM;        // 3.2M
    float* attn16 = v + (long)N_NODES * DIM;        // 12.8M
    float* vmagg  = attn16 + (long)NEDGE * EXP_HEADS;  // 3.2M
    float* a8buf  = q;  // aliases q+k (dead after edge_attn); 6.4M
    unsigned* perm    = (unsigned*)(vmagg + (long)N_NODES * DIM);  // 800k
    unsigned* cnt     = perm + NEDGE;                              // 50k
    unsigned* offsets = cnt + N_NODES;                             // 50001
    unsigned* cursor  = offsets + N_NODES + 1;                     // 50k

    hipMemsetAsync(cnt, 0, (size_t)N_NODES * sizeof(unsigned), stream);

    float* out1 = (float*)d_out;               // [N, 64]
    float* out2 = out1 + (long)N_NODES * DIM;  // [8, E]

    qkv_kernel<<<(N_NODES * DIM + 255) / 256, 256, 0, stream>>>(x, Wq, Wk, Wv, q, k, v);
    hist_kernel<<<(NEDGE + 255) / 256, 256, 0, stream>>>(eidx, cnt);
    scan_kernel<<<1, SCAN_T, 0, stream>>>(cnt, offsets, cursor);
    scatter_kernel<<<(NEDGE + 255) / 256, 256, 0, stream>>>(eidx, cursor, perm);
    edge_attn_kernel<<<NEDGE / 4, 256, 0, stream>>>(edges, eidx, q, k, Wek, Wexp, temp, attn16);
    node_kernel<<<N_NODES / 4, 256, 0, stream>>>(edges, eidx, v, attn16, offsets, perm,
                                                 Wev, Wsq, bsq, a8buf, vmagg);
    transpose_kernel<<<(NEDGE + 255) / 256, 256, 0, stream>>>(a8buf, out2);
    out_kernel<<<(N_NODES * DIM + 255) / 256, 256, 0, stream>>>(vmagg, Wout, bout, out1);
}

// Round 3
// 877.840 us; speedup vs baseline: 1.1922x; 1.1318x over previous
//
#include <hip/hip_runtime.h>

#define N_NODES 50000
#define DIM 64
#define EDGE_DIM 32
#define HEADS 8
#define EXP_HEADS 16
#define NEDGE 800000
#define SCALE 0.35355339059327373f  /* 8^-0.5 */
#define EPS 1e-16f
#define NEG_BIG -1e30f
#define EA_BLOCKS 2048
#define NK_BLOCKS 2048

// ---- Kernel A: q,k,v = x @ {Wq,Wk,Wv} ------------------------------------
__global__ __launch_bounds__(256) void qkv_kernel(
    const float* __restrict__ x, const float* __restrict__ Wq,
    const float* __restrict__ Wk, const float* __restrict__ Wv,
    float* __restrict__ q, float* __restrict__ k, float* __restrict__ v) {
    int gid = blockIdx.x * 256 + threadIdx.x;
    if (gid >= N_NODES * DIM) return;
    int i = gid >> 6, j = gid & 63;
    const float* xr = x + i * DIM;
    float aq = 0.f, ak = 0.f, av = 0.f;
#pragma unroll
    for (int l = 0; l < DIM; ++l) {
        float xv = xr[l];
        aq = fmaf(xv, Wq[l * DIM + j], aq);
        ak = fmaf(xv, Wk[l * DIM + j], ak);
        av = fmaf(xv, Wv[l * DIM + j], av);
    }
    q[gid] = aq; k[gid] = ak; v[gid] = av;
}

// ---- CSR build: histogram --------------------------------------------------
__global__ __launch_bounds__(256) void hist_kernel(
    const int* __restrict__ eidx, unsigned* __restrict__ cnt) {
    int e = blockIdx.x * 256 + threadIdx.x;
    if (e >= NEDGE) return;
    atomicAdd(&cnt[eidx[e]], 1u);
}

// ---- CSR build: single-block exclusive scan over 50k counts ---------------
#define SCAN_T 1024
#define CHUNK 49  /* ceil(50000/1024) */
__global__ __launch_bounds__(SCAN_T) void scan_kernel(
    const unsigned* __restrict__ cnt, unsigned* __restrict__ offsets,
    unsigned* __restrict__ cursor) {
    __shared__ unsigned ps[SCAN_T];
    int t = threadIdx.x;
    int lo = t * CHUNK, hi = min(lo + CHUNK, N_NODES);
    unsigned loc = 0;
    for (int i = lo; i < hi; ++i) loc += cnt[i];
    ps[t] = loc;
    __syncthreads();
    for (int off = 1; off < SCAN_T; off <<= 1) {
        unsigned val = (t >= off) ? ps[t - off] : 0u;
        __syncthreads();
        ps[t] += val;
        __syncthreads();
    }
    unsigned run = ps[t] - loc;  // exclusive base for this chunk
    for (int i = lo; i < hi; ++i) {
        unsigned c = cnt[i];
        offsets[i] = run; cursor[i] = run; run += c;
    }
    if (t == SCAN_T - 1) offsets[N_NODES] = ps[SCAN_T - 1];
}

// ---- CSR build: scatter edge ids into sorted order + inverse perm ---------
__global__ __launch_bounds__(256) void scatter_kernel(
    const int* __restrict__ eidx, unsigned* __restrict__ cursor,
    unsigned* __restrict__ perm, unsigned* __restrict__ iperm) {
    int e = blockIdx.x * 256 + threadIdx.x;
    if (e >= NEDGE) return;
    int dst = eidx[e];
    unsigned pos = atomicAdd(&cursor[dst], 1u);
    perm[pos] = e;
    iperm[e] = pos;
}

// ---- Kernel B: per-edge logits in SORTED order (no LDS) --------------------
__global__ __launch_bounds__(256) void edge_attn_kernel(
    const float* __restrict__ edges, const int* __restrict__ eidx,
    const float* __restrict__ q, const float* __restrict__ k,
    const float* __restrict__ Wek, const float* __restrict__ Wexp,
    const float* __restrict__ temp, const unsigned* __restrict__ perm,
    float* __restrict__ attn16s) {
    int tid = threadIdx.x;
    int w = tid >> 6, lane = tid & 63;
    // Wek column for this lane in registers (loaded once per block)
    float wek[EDGE_DIM];
#pragma unroll
    for (int l = 0; l < EDGE_DIM; ++l) wek[l] = Wek[l * DIM + lane];
    float wexp[HEADS];
#pragma unroll
    for (int h = 0; h < HEADS; ++h) wexp[h] = Wexp[h * EXP_HEADS + (lane & 15)];
    float invt = SCALE / temp[0];
    for (int slot = blockIdx.x * 4 + w; slot < NEDGE; slot += EA_BLOCKS * 4) {
        int e   = __builtin_amdgcn_readfirstlane((int)perm[slot]);
        int dst = __builtin_amdgcn_readfirstlane(eidx[e]);
        int src = __builtin_amdgcn_readfirstlane(eidx[NEDGE + e]);
        const float* __restrict__ ep = edges + (long)e * EDGE_DIM;  // uniform -> s_load
        float ek = 0.f;
#pragma unroll
        for (int l = 0; l < EDGE_DIM; ++l) ek = fmaf(ep[l], wek[l], ek);
        float p = q[(long)dst * DIM + lane] * (k[(long)src * DIM + lane] + ek);
        p += __shfl_xor(p, 1);
        p += __shfl_xor(p, 2);
        p += __shfl_xor(p, 4);
        float s = p * invt;  // head logit, valid on all lanes of each 8-group
        float a = 0.f;
#pragma unroll
        for (int h = 0; h < HEADS; ++h) a = fmaf(__shfl(s, h * 8), wexp[h], a);
        if (lane < EXP_HEADS) attn16s[(long)slot * EXP_HEADS + lane] = a;
    }
}

// ---- Kernel C: per-node segment softmax + Wsq + PV aggregation -------------
__global__ __launch_bounds__(256) void node_kernel(
    const float* __restrict__ edges, const int* __restrict__ eidx,
    const float* __restrict__ v, const float* __restrict__ attn16s,
    const unsigned* __restrict__ offsets, const unsigned* __restrict__ perm,
    const float* __restrict__ Wev, const float* __restrict__ Wsq,
    const float* __restrict__ bsq,
    float* __restrict__ a8s, float* __restrict__ vmagg) {
    int tid = threadIdx.x;
    int w = tid >> 6, lane = tid & 63;
    int h = lane >> 3, d = lane & 7;
    int g = lane >> 4, eh = lane & 15;
    float wsq[EXP_HEADS];
#pragma unroll
    for (int j = 0; j < EXP_HEADS; ++j) wsq[j] = Wsq[j * HEADS + h];
    float bsq_r = bsq[h];
    for (int n = blockIdx.x * 4 + w; n < N_NODES; n += NK_BLOCKS * 4) {
        unsigned nb = offsets[n];
        int deg = (int)(offsets[n + 1] - nb);
        // online softmax stats, 4 edges/iter, coalesced (sorted attn16s)
        float m = NEG_BIG, s = 0.f;
        for (int j0 = 0; j0 < deg; j0 += 4) {
            int j = j0 + g;
            if (j < deg) {
                float a = attn16s[(long)(nb + j) * EXP_HEADS + eh];
                float mn = fmaxf(m, a);
                s = s * __expf(m - mn) + __expf(a - mn);
                m = mn;
            }
        }
#pragma unroll
        for (int off = 16; off < 64; off <<= 1) {
            float m2 = __shfl_xor(m, off), s2 = __shfl_xor(s, off);
            float mn = fmaxf(m, m2);
            s = s * __expf(m - mn) + s2 * __expf(m2 - mn);
            m = mn;
        }
        float rs = 1.f / (s + EPS);
        // PV: acc = sum a8*v[src]; t[h][l] = sum a8*edges[l] (Wev factored out)
        float acc = 0.f, t0 = 0.f, t1 = 0.f, t2 = 0.f, t3 = 0.f;
        for (int j = 0; j < deg; ++j) {
            long slot = (long)nb + j;
            int e   = __builtin_amdgcn_readfirstlane((int)perm[slot]);
            int src = __builtin_amdgcn_readfirstlane(eidx[NEDGE + e]);
            float aval = attn16s[slot * EXP_HEADS + eh];
            float a = __expf(aval - m) * rs;
            float a8 = bsq_r;
#pragma unroll
            for (int jj = 0; jj < EXP_HEADS; ++jj) a8 = fmaf(__shfl(a, jj), wsq[jj], a8);
            if (d == 0) a8s[slot * HEADS + h] = a8;  // coalesced 32B, sorted
            float erow = edges[(long)e * EDGE_DIM + (lane & 31)];
            float vv = v[(long)src * DIM + lane];
            acc = fmaf(a8, vv, acc);
            t0 = fmaf(a8, __shfl(erow, d * 4 + 0), t0);
            t1 = fmaf(a8, __shfl(erow, d * 4 + 1), t1);
            t2 = fmaf(a8, __shfl(erow, d * 4 + 2), t2);
            t3 = fmaf(a8, __shfl(erow, d * 4 + 3), t3);
        }
        // ev = t[h][:] @ Wev — t[h][l] lives on lane h*8+(l>>2), reg t_{l&3}
        float ev = 0.f;
#pragma unroll
        for (int l = 0; l < EDGE_DIM; ++l) {
            float tv = ((l & 3) == 0) ? t0 : ((l & 3) == 1) ? t1 : ((l & 3) == 2) ? t2 : t3;
            float tl = __shfl(tv, h * 8 + (l >> 2));
            ev = fmaf(tl, Wev[l * DIM + lane], ev);
        }
        vmagg[(long)n * DIM + lane] = v[(long)n * DIM + lane] - (acc + ev);
    }
}

// ---- transpose a8s (sorted [E,8]) -> attn.T [8,E] via iperm ---------------
__global__ __launch_bounds__(256) void transpose_kernel(
    const float* __restrict__ a8s, const unsigned* __restrict__ iperm,
    float* __restrict__ out2) {
    int e = blockIdx.x * 256 + threadIdx.x;
    if (e >= NEDGE) return;
    long sj = iperm[e];
    const float4* p = (const float4*)(a8s + sj * HEADS);
    float4 lo = p[0], hi = p[1];
    out2[0L * NEDGE + e] = lo.x; out2[1L * NEDGE + e] = lo.y;
    out2[2L * NEDGE + e] = lo.z; out2[3L * NEDGE + e] = lo.w;
    out2[4L * NEDGE + e] = hi.x; out2[5L * NEDGE + e] = hi.y;
    out2[6L * NEDGE + e] = hi.z; out2[7L * NEDGE + e] = hi.w;
}

// ---- Kernel E: out = vmagg @ Wout + bout -----------------------------------
__global__ __launch_bounds__(256) void out_kernel(
    const float* __restrict__ vmagg, const float* __restrict__ Wout,
    const float* __restrict__ bout, float* __restrict__ out) {
    int gid = blockIdx.x * 256 + threadIdx.x;
    if (gid >= N_NODES * DIM) return;
    int i = gid >> 6, j = gid & 63;
    float acc = bout[j];
#pragma unroll
    for (int l = 0; l < DIM; ++l)
        acc = fmaf(vmagg[i * DIM + l], Wout[l * DIM + j], acc);
    out[gid] = acc;
}

extern "C" void kernel_launch(void* const* d_in, const int* in_sizes, int n_in,
                              void* d_out, int out_size, void* d_ws, size_t ws_size,
                              hipStream_t stream) {
    const float* x     = (const float*)d_in[0];
    const float* edges = (const float*)d_in[1];
    const int*   eidx  = (const int*)d_in[2];
    const float* Wq    = (const float*)d_in[3];
    const float* Wk    = (const float*)d_in[4];
    const float* Wv    = (const float*)d_in[5];
    const float* Wek   = (const float*)d_in[6];
    const float* Wev   = (const float*)d_in[7];
    const float* Wexp  = (const float*)d_in[8];
    const float* Wsq   = (const float*)d_in[9];
    const float* bsq   = (const float*)d_in[10];
    const float* Wout  = (const float*)d_in[11];
    const float* bout  = (const float*)d_in[12];
    const float* temp  = (const float*)d_in[13];

    float* ws = (float*)d_ws;
    float* q       = ws;                                  // 3.2M floats
    float* k       = q + (long)N_NODES * DIM;             // 3.2M
    float* v       = k + (long)N_NODES * DIM;             // 3.2M
    float* attn16s = v + (long)N_NODES * DIM;             // 12.8M (sorted)
    float* vmagg   = attn16s + (long)NEDGE * EXP_HEADS;   // 3.2M
    float* a8s     = q;  // aliases q+k (dead after edge_attn); 6.4M
    unsigned* perm    = (unsigned*)(vmagg + (long)N_NODES * DIM);  // 800k
    unsigned* iperm   = perm + NEDGE;                              // 800k
    unsigned* cnt     = iperm + NEDGE;                             // 50k
    unsigned* offsets = cnt + N_NODES;                             // 50001
    unsigned* cursor  = offsets + N_NODES + 1;                     // 50k

    hipMemsetAsync(cnt, 0, (size_t)N_NODES * sizeof(unsigned), stream);

    float* out1 = (float*)d_out;               // [N, 64]
    float* out2 = out1 + (long)N_NODES * DIM;  // [8, E]

    qkv_kernel<<<(N_NODES * DIM + 255) / 256, 256, 0, stream>>>(x, Wq, Wk, Wv, q, k, v);
    hist_kernel<<<(NEDGE + 255) / 256, 256, 0, stream>>>(eidx, cnt);
    scan_kernel<<<1, SCAN_T, 0, stream>>>(cnt, offsets, cursor);
    scatter_kernel<<<(NEDGE + 255) / 256, 256, 0, stream>>>(eidx, cursor, perm, iperm);
    edge_attn_kernel<<<EA_BLOCKS, 256, 0, stream>>>(edges, eidx, q, k, Wek, Wexp, temp, perm, attn16s);
    node_kernel<<<NK_BLOCKS, 256, 0, stream>>>(edges, eidx, v, attn16s, offsets, perm,
                                               Wev, Wsq, bsq, a8s, vmagg);
    transpose_kernel<<<(NEDGE + 255) / 256, 256, 0, stream>>>(a8s, iperm, out2);
    out_kernel<<<(N_NODES * DIM + 255) / 256, 256, 0, stream>>>(vmagg, Wout, bout, out1);
}

// Round 4
// 654.327 us; speedup vs baseline: 1.5995x; 1.3416x over previous
//
#include <hip/hip_runtime.h>

#define N_NODES 50000
#define DIM 64
#define EDGE_DIM 32
#define HEADS 8
#define EXP_HEADS 16
#define NEDGE 800000
#define SCALE 0.35355339059327373f  /* 8^-0.5 */
#define EPS 1e-16f
#define NEG_BIG -1e30f
#define EA_BLOCKS 2048
#define NK_BLOCKS 2048

// ---- Kernel A: q,k,v = x @ {Wq,Wk,Wv}, 4 nodes per thread ------------------
__global__ __launch_bounds__(256) void qkv_kernel(
    const float* __restrict__ x, const float* __restrict__ Wq,
    const float* __restrict__ Wk, const float* __restrict__ Wv,
    float* __restrict__ q, float* __restrict__ k, float* __restrict__ v) {
    int gid = blockIdx.x * 256 + threadIdx.x;   // (N/4)*64 = 800000 threads
    if (gid >= (N_NODES / 4) * DIM) return;
    int quad = gid >> 6, j = gid & 63;
    long i0 = (long)quad * 4;
    float aq[4] = {0,0,0,0}, ak[4] = {0,0,0,0}, av[4] = {0,0,0,0};
#pragma unroll
    for (int l = 0; l < DIM; ++l) {
        float wq = Wq[l * DIM + j], wk = Wk[l * DIM + j], wv = Wv[l * DIM + j];
#pragma unroll
        for (int r = 0; r < 4; ++r) {
            float xv = x[(i0 + r) * DIM + l];
            aq[r] = fmaf(xv, wq, aq[r]);
            ak[r] = fmaf(xv, wk, ak[r]);
            av[r] = fmaf(xv, wv, av[r]);
        }
    }
#pragma unroll
    for (int r = 0; r < 4; ++r) {
        q[(i0 + r) * DIM + j] = aq[r];
        k[(i0 + r) * DIM + j] = ak[r];
        v[(i0 + r) * DIM + j] = av[r];
    }
}

// ---- CSR build: histogram --------------------------------------------------
__global__ __launch_bounds__(256) void hist_kernel(
    const int* __restrict__ eidx, unsigned* __restrict__ cnt) {
    int e = blockIdx.x * 256 + threadIdx.x;
    if (e >= NEDGE) return;
    atomicAdd(&cnt[eidx[e]], 1u);
}

// ---- CSR build: single-block exclusive scan over 50k counts ---------------
#define SCAN_T 1024
#define CHUNK 49  /* ceil(50000/1024) */
__global__ __launch_bounds__(SCAN_T) void scan_kernel(
    const unsigned* __restrict__ cnt, unsigned* __restrict__ offsets,
    unsigned* __restrict__ cursor) {
    __shared__ unsigned ps[SCAN_T];
    int t = threadIdx.x;
    int lo = t * CHUNK, hi = min(lo + CHUNK, N_NODES);
    unsigned loc = 0;
    for (int i = lo; i < hi; ++i) loc += cnt[i];
    ps[t] = loc;
    __syncthreads();
    for (int off = 1; off < SCAN_T; off <<= 1) {
        unsigned val = (t >= off) ? ps[t - off] : 0u;
        __syncthreads();
        ps[t] += val;
        __syncthreads();
    }
    unsigned run = ps[t] - loc;  // exclusive base for this chunk
    for (int i = lo; i < hi; ++i) {
        unsigned c = cnt[i];
        offsets[i] = run; cursor[i] = run; run += c;
    }
    if (t == SCAN_T - 1) offsets[N_NODES] = ps[SCAN_T - 1];
}

// ---- CSR build: scatter edge ids + src ids into sorted order ---------------
__global__ __launch_bounds__(256) void scatter_kernel(
    const int* __restrict__ eidx, unsigned* __restrict__ cursor,
    unsigned* __restrict__ perm, unsigned* __restrict__ iperm,
    unsigned* __restrict__ srcs) {
    int e = blockIdx.x * 256 + threadIdx.x;
    if (e >= NEDGE) return;
    int dst = eidx[e];
    unsigned pos = atomicAdd(&cursor[dst], 1u);
    perm[pos] = e;
    iperm[e] = pos;
    srcs[pos] = (unsigned)eidx[NEDGE + e];
}

// ---- Kernel B: per-edge logits in SORTED order (no LDS) --------------------
__global__ __launch_bounds__(256) void edge_attn_kernel(
    const float* __restrict__ edges, const int* __restrict__ eidx,
    const float* __restrict__ q, const float* __restrict__ k,
    const float* __restrict__ Wek, const float* __restrict__ Wexp,
    const float* __restrict__ temp, const unsigned* __restrict__ perm,
    float* __restrict__ attn16s) {
    int tid = threadIdx.x;
    int w = tid >> 6, lane = tid & 63;
    int h = lane >> 3, d = lane & 7;
    float wek[EDGE_DIM];
#pragma unroll
    for (int l = 0; l < EDGE_DIM; ++l) wek[l] = Wek[l * DIM + lane];
    float we0 = Wexp[h * EXP_HEADS + 2 * d];
    float we1 = Wexp[h * EXP_HEADS + 2 * d + 1];
    float invt = SCALE / temp[0];
    for (int slot = blockIdx.x * 4 + w; slot < NEDGE; slot += EA_BLOCKS * 4) {
        int e   = __builtin_amdgcn_readfirstlane((int)perm[slot]);
        int dst = __builtin_amdgcn_readfirstlane(eidx[e]);
        int src = __builtin_amdgcn_readfirstlane(eidx[NEDGE + e]);
        const float* __restrict__ ep = edges + (long)e * EDGE_DIM;
        float ek = 0.f;
#pragma unroll
        for (int l = 0; l < EDGE_DIM; ++l) ek = fmaf(ep[l], wek[l], ek);
        float p = q[(long)dst * DIM + lane] * (k[(long)src * DIM + lane] + ek);
        p += __shfl_xor(p, 1);
        p += __shfl_xor(p, 2);
        p += __shfl_xor(p, 4);
        float s = p * invt;  // logit for head h, all lanes of 8-group
        // a[eh] = sum_h s_h * Wexp[h][eh]: butterfly over h (xor 8,16,32)
        float c0 = s * we0, c1 = s * we1;
        c0 += __shfl_xor(c0, 8);  c1 += __shfl_xor(c1, 8);
        c0 += __shfl_xor(c0, 16); c1 += __shfl_xor(c1, 16);
        c0 += __shfl_xor(c0, 32); c1 += __shfl_xor(c1, 32);
        if (lane < 8) {
            float2 cc; cc.x = c0; cc.y = c1;
            *(float2*)&attn16s[(long)slot * EXP_HEADS + 2 * lane] = cc;
        }
    }
}

// ---- Kernel C: per-node segment softmax + Wsq + PV aggregation -------------
// 4 edges per iteration; a8 = attn@Wsq via 16-lane halving butterfly.
__global__ __launch_bounds__(256) void node_kernel(
    const float* __restrict__ edges,
    const float* __restrict__ v, const float* __restrict__ attn16s,
    const unsigned* __restrict__ offsets, const unsigned* __restrict__ perm,
    const unsigned* __restrict__ srcs,
    const float* __restrict__ Wev, const float* __restrict__ Wsq,
    const float* __restrict__ bsq,
    float* __restrict__ a8s, float* __restrict__ vmagg) {
    int tid = threadIdx.x;
    int w = tid >> 6, lane = tid & 63;
    int g = lane >> 4, t16 = lane & 15;
    int h = lane >> 3, d = lane & 7;
    // Wsq row for this lane's expanded head
    float wsq[HEADS];
#pragma unroll
    for (int j = 0; j < HEADS; ++j) wsq[j] = Wsq[t16 * HEADS + j];
    // butterfly output head for this lane: bit-reverse-3 of t16 (low 3 bits)
    int hmap = 4 * (t16 & 1) + 2 * ((t16 >> 1) & 1) + ((t16 >> 2) & 1);
    // source lane (within 16) holding head h: bit-reverse-3 of h
    int ih = ((h >> 2) & 1) | (((h >> 1) & 1) << 1) | ((h & 1) << 2);
    float bs_h = bsq[h], bs_w = bsq[hmap];
    bool b0 = (t16 & 1), b1 = (t16 & 2), b2 = (t16 & 4);

    for (int n = blockIdx.x * 4 + w; n < N_NODES; n += NK_BLOCKS * 4) {
        unsigned nb = offsets[n];
        int deg = (int)(offsets[n + 1] - nb);
        // --- online softmax stats, 4 edges/iter, coalesced ---
        float m = NEG_BIG, s = 0.f;
        for (int j0 = 0; j0 < deg; j0 += 4) {
            float a = attn16s[(long)(nb + j0) * EXP_HEADS + lane];
            if (j0 + g < deg) {
                float mn = fmaxf(m, a);
                s = s * __expf(m - mn) + __expf(a - mn);
                m = mn;
            }
        }
#pragma unroll
        for (int off = 16; off < 64; off <<= 1) {
            float m2 = __shfl_xor(m, off), s2 = __shfl_xor(s, off);
            float mn = fmaxf(m, m2);
            s = s * __expf(m - mn) + s2 * __expf(m2 - mn);
            m = mn;
        }
        float rs = 1.f / (s + EPS);
        // --- PV: 4 edges/iter ---
        float acc = 0.f, t0 = 0.f, t1 = 0.f, t2 = 0.f, t3 = 0.f;
        for (int j0 = 0; j0 < deg; j0 += 4) {
            float a = attn16s[(long)(nb + j0) * EXP_HEADS + lane];
            float p = (j0 + g < deg) ? __expf(a - m) * rs : 0.f;
            // products p * Wsq[t16][h] for all 8 h
            float v0 = p * wsq[0], v1 = p * wsq[1], v2 = p * wsq[2], v3 = p * wsq[3];
            float v4 = p * wsq[4], v5 = p * wsq[5], v6 = p * wsq[6], v7 = p * wsq[7];
            // halving butterfly over the 16-lane group
            float q0, q1, q2, q3, n0, n1, s8;
            q0 = (b0 ? v4 : v0) + __shfl_xor(b0 ? v0 : v4, 1);
            q1 = (b0 ? v5 : v1) + __shfl_xor(b0 ? v1 : v5, 1);
            q2 = (b0 ? v6 : v2) + __shfl_xor(b0 ? v2 : v6, 1);
            q3 = (b0 ? v7 : v3) + __shfl_xor(b0 ? v3 : v7, 1);
            n0 = (b1 ? q2 : q0) + __shfl_xor(b1 ? q0 : q2, 2);
            n1 = (b1 ? q3 : q1) + __shfl_xor(b1 ? q1 : q3, 2);
            s8 = (b2 ? n1 : n0) + __shfl_xor(b2 ? n0 : n1, 4);
            float a8sum = s8 + __shfl_xor(s8, 8);  // lane holds a8[hmap] (no bias)
            // per-edge accumulation (wave-uniform guards)
            const unsigned* pp = perm + nb + j0;
            const unsigned* sp = srcs + nb + j0;
#pragma unroll
            for (int g2 = 0; g2 < 4; ++g2) {
                if (j0 + g2 < deg) {
                    int e_g = __builtin_amdgcn_readfirstlane((int)pp[g2]);
                    int s_g = __builtin_amdgcn_readfirstlane((int)sp[g2]);
                    float a8 = __shfl(a8sum, g2 * 16 + ih) + bs_h;
                    float vv = v[(long)s_g * DIM + lane];
                    acc = fmaf(a8, vv, acc);
                    float4 ed = *(const float4*)(edges + (long)e_g * EDGE_DIM + d * 4);
                    t0 = fmaf(a8, ed.x, t0);
                    t1 = fmaf(a8, ed.y, t1);
                    t2 = fmaf(a8, ed.z, t2);
                    t3 = fmaf(a8, ed.w, t3);
                }
            }
            // a8 output (sorted layout), one lane per (edge, head)
            if (t16 < 8 && g < deg - j0)
                a8s[(long)(nb + j0 + g) * HEADS + hmap] = a8sum + bs_w;
        }
        // ev = t[h][:] @ Wev — t[h][l] on lane h*8+(l>>2), reg t_{l&3}
        float ev = 0.f;
#pragma unroll
        for (int l = 0; l < EDGE_DIM; ++l) {
            float tv = ((l & 3) == 0) ? t0 : ((l & 3) == 1) ? t1 : ((l & 3) == 2) ? t2 : t3;
            float tl = __shfl(tv, h * 8 + (l >> 2));
            ev = fmaf(tl, Wev[l * DIM + lane], ev);
        }
        vmagg[(long)n * DIM + lane] = v[(long)n * DIM + lane] - (acc + ev);
    }
}

// ---- transpose a8s (sorted [E,8]) -> attn.T [8,E] via iperm ---------------
__global__ __launch_bounds__(256) void transpose_kernel(
    const float* __restrict__ a8s, const unsigned* __restrict__ iperm,
    float* __restrict__ out2) {
    int e = blockIdx.x * 256 + threadIdx.x;
    if (e >= NEDGE) return;
    long sj = iperm[e];
    const float4* p = (const float4*)(a8s + sj * HEADS);
    float4 lo = p[0], hi = p[1];
    out2[0L * NEDGE + e] = lo.x; out2[1L * NEDGE + e] = lo.y;
    out2[2L * NEDGE + e] = lo.z; out2[3L * NEDGE + e] = lo.w;
    out2[4L * NEDGE + e] = hi.x; out2[5L * NEDGE + e] = hi.y;
    out2[6L * NEDGE + e] = hi.z; out2[7L * NEDGE + e] = hi.w;
}

// ---- Kernel E: out = vmagg @ Wout + bout, 4 nodes per thread ---------------
__global__ __launch_bounds__(256) void out_kernel(
    const float* __restrict__ vmagg, const float* __restrict__ Wout,
    const float* __restrict__ bout, float* __restrict__ out) {
    int gid = blockIdx.x * 256 + threadIdx.x;
    if (gid >= (N_NODES / 4) * DIM) return;
    int quad = gid >> 6, j = gid & 63;
    long i0 = (long)quad * 4;
    float b = bout[j];
    float ac[4] = {b, b, b, b};
#pragma unroll
    for (int l = 0; l < DIM; ++l) {
        float wv = Wout[l * DIM + j];
#pragma unroll
        for (int r = 0; r < 4; ++r)
            ac[r] = fmaf(vmagg[(i0 + r) * DIM + l], wv, ac[r]);
    }
#pragma unroll
    for (int r = 0; r < 4; ++r) out[(i0 + r) * DIM + j] = ac[r];
}

extern "C" void kernel_launch(void* const* d_in, const int* in_sizes, int n_in,
                              void* d_out, int out_size, void* d_ws, size_t ws_size,
                              hipStream_t stream) {
    const float* x     = (const float*)d_in[0];
    const float* edges = (const float*)d_in[1];
    const int*   eidx  = (const int*)d_in[2];
    const float* Wq    = (const float*)d_in[3];
    const float* Wk    = (const float*)d_in[4];
    const float* Wv    = (const float*)d_in[5];
    const float* Wek   = (const float*)d_in[6];
    const float* Wev   = (const float*)d_in[7];
    const float* Wexp  = (const float*)d_in[8];
    const float* Wsq   = (const float*)d_in[9];
    const float* bsq   = (const float*)d_in[10];
    const float* Wout  = (const float*)d_in[11];
    const float* bout  = (const float*)d_in[12];
    const float* temp  = (const float*)d_in[13];

    float* ws = (float*)d_ws;
    float* q       = ws;                                  // 3.2M floats
    float* k       = q + (long)N_NODES * DIM;             // 3.2M
    float* v       = k + (long)N_NODES * DIM;             // 3.2M
    float* attn16s = v + (long)N_NODES * DIM;             // 12.8M (sorted)
    float* vmagg   = attn16s + (long)NEDGE * EXP_HEADS;   // 3.2M
    float* a8s     = q;  // aliases q+k (dead after edge_attn); 6.4M
    unsigned* perm    = (unsigned*)(vmagg + (long)N_NODES * DIM);  // 800k
    unsigned* iperm   = perm + NEDGE;                              // 800k
    unsigned* srcs    = iperm + NEDGE;                             // 800k
    unsigned* cnt     = srcs + NEDGE;                              // 50k
    unsigned* offsets = cnt + N_NODES;                             // 50001
    unsigned* cursor  = offsets + N_NODES + 1;                     // 50k

    hipMemsetAsync(cnt, 0, (size_t)N_NODES * sizeof(unsigned), stream);

    float* out1 = (float*)d_out;               // [N, 64]
    float* out2 = out1 + (long)N_NODES * DIM;  // [8, E]

    qkv_kernel<<<(N_NODES / 4 * DIM + 255) / 256, 256, 0, stream>>>(x, Wq, Wk, Wv, q, k, v);
    hist_kernel<<<(NEDGE + 255) / 256, 256, 0, stream>>>(eidx, cnt);
    scan_kernel<<<1, SCAN_T, 0, stream>>>(cnt, offsets, cursor);
    scatter_kernel<<<(NEDGE + 255) / 256, 256, 0, stream>>>(eidx, cursor, perm, iperm, srcs);
    edge_attn_kernel<<<EA_BLOCKS, 256, 0, stream>>>(edges, eidx, q, k, Wek, Wexp, temp, perm, attn16s);
    node_kernel<<<NK_BLOCKS, 256, 0, stream>>>(edges, v, attn16s, offsets, perm, srcs,
                                               Wev, Wsq, bsq, a8s, vmagg);
    transpose_kernel<<<(NEDGE + 255) / 256, 256, 0, stream>>>(a8s, iperm, out2);
    out_kernel<<<(N_NODES / 4 * DIM + 255) / 256, 256, 0, stream>>>(vmagg, Wout, bout, out1);
}

// Round 5
// 560.956 us; speedup vs baseline: 1.8657x; 1.1665x over previous
//
#include <hip/hip_runtime.h>

#define N_NODES 50000
#define DIM 64
#define EDGE_DIM 32
#define HEADS 8
#define EXP_HEADS 16
#define NEDGE 800000
#define SCALE 0.35355339059327373f  /* 8^-0.5 */
#define EPS 1e-16f
#define NEG_BIG -1e30f
#define EA_BLOCKS 2048

#define RFL(x) __builtin_amdgcn_readfirstlane(x)

// ---- Kernel A: q,k,v = x @ {Wq,Wk,Wv}, 4 nodes per thread ------------------
__global__ __launch_bounds__(256) void qkv_kernel(
    const float* __restrict__ x, const float* __restrict__ Wq,
    const float* __restrict__ Wk, const float* __restrict__ Wv,
    float* __restrict__ q, float* __restrict__ k, float* __restrict__ v) {
    int gid = blockIdx.x * 256 + threadIdx.x;
    if (gid >= (N_NODES / 4) * DIM) return;
    int quad = gid >> 6, j = gid & 63;
    long i0 = (long)quad * 4;
    float aq[4] = {0,0,0,0}, ak[4] = {0,0,0,0}, av[4] = {0,0,0,0};
#pragma unroll
    for (int l = 0; l < DIM; ++l) {
        float wq = Wq[l * DIM + j], wk = Wk[l * DIM + j], wv = Wv[l * DIM + j];
#pragma unroll
        for (int r = 0; r < 4; ++r) {
            float xv = x[(i0 + r) * DIM + l];
            aq[r] = fmaf(xv, wq, aq[r]);
            ak[r] = fmaf(xv, wk, ak[r]);
            av[r] = fmaf(xv, wv, av[r]);
        }
    }
#pragma unroll
    for (int r = 0; r < 4; ++r) {
        q[(i0 + r) * DIM + j] = aq[r];
        k[(i0 + r) * DIM + j] = ak[r];
        v[(i0 + r) * DIM + j] = av[r];
    }
}

// ---- CSR build: histogram --------------------------------------------------
__global__ __launch_bounds__(256) void hist_kernel(
    const int* __restrict__ eidx, unsigned* __restrict__ cnt) {
    int e = blockIdx.x * 256 + threadIdx.x;
    if (e >= NEDGE) return;
    atomicAdd(&cnt[eidx[e]], 1u);
}

// ---- CSR build: single-block exclusive scan over 50k counts ---------------
#define SCAN_T 1024
#define CHUNK 49
__global__ __launch_bounds__(SCAN_T) void scan_kernel(
    const unsigned* __restrict__ cnt, unsigned* __restrict__ offsets,
    unsigned* __restrict__ cursor) {
    __shared__ unsigned ps[SCAN_T];
    int t = threadIdx.x;
    int lo = t * CHUNK, hi = min(lo + CHUNK, N_NODES);
    unsigned loc = 0;
    for (int i = lo; i < hi; ++i) loc += cnt[i];
    ps[t] = loc;
    __syncthreads();
    for (int off = 1; off < SCAN_T; off <<= 1) {
        unsigned val = (t >= off) ? ps[t - off] : 0u;
        __syncthreads();
        ps[t] += val;
        __syncthreads();
    }
    unsigned run = ps[t] - loc;
    for (int i = lo; i < hi; ++i) {
        unsigned c = cnt[i];
        offsets[i] = run; cursor[i] = run; run += c;
    }
    if (t == SCAN_T - 1) offsets[N_NODES] = ps[SCAN_T - 1];
}

// ---- CSR build: scatter edge/dst/src ids into sorted order -----------------
__global__ __launch_bounds__(256) void scatter_kernel(
    const int* __restrict__ eidx, unsigned* __restrict__ cursor,
    unsigned* __restrict__ perm, unsigned* __restrict__ iperm,
    unsigned* __restrict__ srcs, unsigned* __restrict__ dsts) {
    int e = blockIdx.x * 256 + threadIdx.x;
    if (e >= NEDGE) return;
    int dst = eidx[e];
    unsigned pos = atomicAdd(&cursor[dst], 1u);
    perm[pos] = e;
    iperm[e] = pos;
    srcs[pos] = (unsigned)eidx[NEDGE + e];
    dsts[pos] = (unsigned)dst;
}

// ---- Kernel B: per-edge logits, 2 slots per wave iteration -----------------
__global__ __launch_bounds__(256) void edge_attn_kernel(
    const float* __restrict__ edges,
    const float* __restrict__ q, const float* __restrict__ k,
    const float* __restrict__ Wek, const float* __restrict__ Wexp,
    const float* __restrict__ temp, const unsigned* __restrict__ perm,
    const unsigned* __restrict__ dsts, const unsigned* __restrict__ srcs,
    float* __restrict__ attn16s) {
    int tid = threadIdx.x;
    int w = tid >> 6, lane = tid & 63;
    int h = lane >> 3, d = lane & 7;
    float wek[EDGE_DIM];
#pragma unroll
    for (int l = 0; l < EDGE_DIM; ++l) wek[l] = Wek[l * DIM + lane];
    float we0 = Wexp[h * EXP_HEADS + 2 * d];
    float we1 = Wexp[h * EXP_HEADS + 2 * d + 1];
    float invt = SCALE / temp[0];
    for (int slot = blockIdx.x * 8 + w * 2; slot < NEDGE; slot += EA_BLOCKS * 8) {
        int eA   = RFL((int)perm[slot]);     int eB   = RFL((int)perm[slot + 1]);
        int dstA = RFL((int)dsts[slot]);     int dstB = RFL((int)dsts[slot + 1]);
        int srcA = RFL((int)srcs[slot]);     int srcB = RFL((int)srcs[slot + 1]);
        const float* __restrict__ epA = edges + (long)eA * EDGE_DIM;
        const float* __restrict__ epB = edges + (long)eB * EDGE_DIM;
        float ekA0 = 0.f, ekA1 = 0.f, ekB0 = 0.f, ekB1 = 0.f;
#pragma unroll
        for (int l = 0; l < EDGE_DIM; l += 2) {
            ekA0 = fmaf(epA[l],     wek[l],     ekA0);
            ekA1 = fmaf(epA[l + 1], wek[l + 1], ekA1);
            ekB0 = fmaf(epB[l],     wek[l],     ekB0);
            ekB1 = fmaf(epB[l + 1], wek[l + 1], ekB1);
        }
        float pA = q[(long)dstA * DIM + lane] * (k[(long)srcA * DIM + lane] + ekA0 + ekA1);
        float pB = q[(long)dstB * DIM + lane] * (k[(long)srcB * DIM + lane] + ekB0 + ekB1);
        pA += __shfl_xor(pA, 1); pB += __shfl_xor(pB, 1);
        pA += __shfl_xor(pA, 2); pB += __shfl_xor(pB, 2);
        pA += __shfl_xor(pA, 4); pB += __shfl_xor(pB, 4);
        float sA = pA * invt, sB = pB * invt;
        float cA0 = sA * we0, cA1 = sA * we1, cB0 = sB * we0, cB1 = sB * we1;
        cA0 += __shfl_xor(cA0, 8);  cA1 += __shfl_xor(cA1, 8);
        cB0 += __shfl_xor(cB0, 8);  cB1 += __shfl_xor(cB1, 8);
        cA0 += __shfl_xor(cA0, 16); cA1 += __shfl_xor(cA1, 16);
        cB0 += __shfl_xor(cB0, 16); cB1 += __shfl_xor(cB1, 16);
        cA0 += __shfl_xor(cA0, 32); cA1 += __shfl_xor(cA1, 32);
        cB0 += __shfl_xor(cB0, 32); cB1 += __shfl_xor(cB1, 32);
        if (lane < 8) {
            float2 ca; ca.x = cA0; ca.y = cA1;
            float2 cb; cb.x = cB0; cb.y = cB1;
            *(float2*)&attn16s[(long)slot * EXP_HEADS + 2 * lane] = ca;
            *(float2*)&attn16s[(long)(slot + 1) * EXP_HEADS + 2 * lane] = cb;
        }
    }
}

// ---- Kernel C1: softmax stats, thread per (node, expanded head) ------------
__global__ __launch_bounds__(256) void stats_kernel(
    const float* __restrict__ attn16s, const unsigned* __restrict__ offsets,
    float2* __restrict__ stats) {
    int gid = blockIdx.x * 256 + threadIdx.x;   // N*16 = 800k threads
    if (gid >= N_NODES * EXP_HEADS) return;
    int n = gid >> 4, eh = gid & 15;
    unsigned nb = offsets[n];
    int deg = (int)(offsets[n + 1] - nb);
    float m = NEG_BIG, s = 0.f;
    for (int j = 0; j < deg; ++j) {
        float a = attn16s[(long)(nb + j) * EXP_HEADS + eh];
        float mn = fmaxf(m, a);
        s = s * __expf(m - mn) + __expf(a - mn);
        m = mn;
    }
    float2 st; st.x = m; st.y = 1.f / (s + EPS);
    stats[gid] = st;
}

// ---- Kernel C2: edge-parallel a8 = softmax(attn)@Wsq + bsq -----------------
__global__ __launch_bounds__(256) void a8_kernel(
    const float* __restrict__ attn16s, const unsigned* __restrict__ dsts,
    const float2* __restrict__ stats, const float* __restrict__ Wsq,
    const float* __restrict__ bsq, float* __restrict__ a8s) {
    int tid = threadIdx.x;
    int w = tid >> 6, lane = tid & 63;
    int g = lane >> 4, t16 = lane & 15;
    long slot0 = ((long)blockIdx.x * 4 + w) * 4;   // 4 slots per wave
    float wsq[HEADS];
#pragma unroll
    for (int j = 0; j < HEADS; ++j) wsq[j] = Wsq[t16 * HEADS + j];
    int hmap = 4 * (t16 & 1) + 2 * ((t16 >> 1) & 1) + ((t16 >> 2) & 1);
    float bs_w = bsq[hmap];
    bool b0 = (t16 & 1), b1 = (t16 & 2), b2 = (t16 & 4);

    float a = attn16s[slot0 * EXP_HEADS + lane];          // coalesced 256B
    int dstg = (int)dsts[slot0 + g];
    float2 st = stats[(long)dstg * EXP_HEADS + t16];
    float p = __expf(a - st.x) * st.y;
    float v0 = p * wsq[0], v1 = p * wsq[1], v2 = p * wsq[2], v3 = p * wsq[3];
    float v4 = p * wsq[4], v5 = p * wsq[5], v6 = p * wsq[6], v7 = p * wsq[7];
    float q0, q1, q2, q3, n0, n1, s8;
    q0 = (b0 ? v4 : v0) + __shfl_xor(b0 ? v0 : v4, 1);
    q1 = (b0 ? v5 : v1) + __shfl_xor(b0 ? v1 : v5, 1);
    q2 = (b0 ? v6 : v2) + __shfl_xor(b0 ? v2 : v6, 1);
    q3 = (b0 ? v7 : v3) + __shfl_xor(b0 ? v3 : v7, 1);
    n0 = (b1 ? q2 : q0) + __shfl_xor(b1 ? q0 : q2, 2);
    n1 = (b1 ? q3 : q1) + __shfl_xor(b1 ? q1 : q3, 2);
    s8 = (b2 ? n1 : n0) + __shfl_xor(b2 ? n0 : n1, 4);
    float a8sum = s8 + __shfl_xor(s8, 8);
    if (t16 < 8) a8s[(slot0 + g) * HEADS + hmap] = a8sum + bs_w;
}

// ---- Kernel C3: per-node aggregation (no shfl in loop) ---------------------
__global__ __launch_bounds__(256) void agg_kernel(
    const float* __restrict__ edges, const float* __restrict__ v,
    const float* __restrict__ a8s,
    const unsigned* __restrict__ offsets, const unsigned* __restrict__ perm,
    const unsigned* __restrict__ srcs,
    const float* __restrict__ Wev, float* __restrict__ vmagg) {
    int tid = threadIdx.x;
    int w = tid >> 6, lane = tid & 63;
    int h = lane >> 3, d = lane & 7;
    int n = blockIdx.x * 4 + w;    // N_NODES % 4 == 0, grid exact
    unsigned nb = offsets[n];
    int deg = (int)(offsets[n + 1] - nb);
    float acc = 0.f, t0 = 0.f, t1 = 0.f, t2 = 0.f, t3 = 0.f;
    int j = 0;
    for (; j + 4 <= deg; j += 4) {
#pragma unroll
        for (int g2 = 0; g2 < 4; ++g2) {
            long slot = (long)nb + j + g2;
            int e_g = RFL((int)perm[slot]);
            int s_g = RFL((int)srcs[slot]);
            float a8 = a8s[slot * HEADS + h];
            float vv = v[(long)s_g * DIM + lane];
            float4 ed = *(const float4*)(edges + (long)e_g * EDGE_DIM + d * 4);
            acc = fmaf(a8, vv, acc);
            t0 = fmaf(a8, ed.x, t0);
            t1 = fmaf(a8, ed.y, t1);
            t2 = fmaf(a8, ed.z, t2);
            t3 = fmaf(a8, ed.w, t3);
        }
    }
    for (; j < deg; ++j) {
        long slot = (long)nb + j;
        int e_g = RFL((int)perm[slot]);
        int s_g = RFL((int)srcs[slot]);
        float a8 = a8s[slot * HEADS + h];
        float vv = v[(long)s_g * DIM + lane];
        float4 ed = *(const float4*)(edges + (long)e_g * EDGE_DIM + d * 4);
        acc = fmaf(a8, vv, acc);
        t0 = fmaf(a8, ed.x, t0);
        t1 = fmaf(a8, ed.y, t1);
        t2 = fmaf(a8, ed.z, t2);
        t3 = fmaf(a8, ed.w, t3);
    }
    // ev = t[h][:] @ Wev — t[h][l] on lane h*8+(l>>2), reg t_{l&3}
    float ev = 0.f;
#pragma unroll
    for (int l = 0; l < EDGE_DIM; ++l) {
        float tv = ((l & 3) == 0) ? t0 : ((l & 3) == 1) ? t1 : ((l & 3) == 2) ? t2 : t3;
        float tl = __shfl(tv, h * 8 + (l >> 2));
        ev = fmaf(tl, Wev[l * DIM + lane], ev);
    }
    vmagg[(long)n * DIM + lane] = v[(long)n * DIM + lane] - (acc + ev);
}

// ---- transpose a8s (sorted [E,8]) -> attn.T [8,E] via iperm ---------------
__global__ __launch_bounds__(256) void transpose_kernel(
    const float* __restrict__ a8s, const unsigned* __restrict__ iperm,
    float* __restrict__ out2) {
    int e = blockIdx.x * 256 + threadIdx.x;
    if (e >= NEDGE) return;
    long sj = iperm[e];
    const float4* p = (const float4*)(a8s + sj * HEADS);
    float4 lo = p[0], hi = p[1];
    out2[0L * NEDGE + e] = lo.x; out2[1L * NEDGE + e] = lo.y;
    out2[2L * NEDGE + e] = lo.z; out2[3L * NEDGE + e] = lo.w;
    out2[4L * NEDGE + e] = hi.x; out2[5L * NEDGE + e] = hi.y;
    out2[6L * NEDGE + e] = hi.z; out2[7L * NEDGE + e] = hi.w;
}

// ---- Kernel E: out = vmagg @ Wout + bout, 4 nodes per thread ---------------
__global__ __launch_bounds__(256) void out_kernel(
    const float* __restrict__ vmagg, const float* __restrict__ Wout,
    const float* __restrict__ bout, float* __restrict__ out) {
    int gid = blockIdx.x * 256 + threadIdx.x;
    if (gid >= (N_NODES / 4) * DIM) return;
    int quad = gid >> 6, j = gid & 63;
    long i0 = (long)quad * 4;
    float b = bout[j];
    float ac[4] = {b, b, b, b};
#pragma unroll
    for (int l = 0; l < DIM; ++l) {
        float wv = Wout[l * DIM + j];
#pragma unroll
        for (int r = 0; r < 4; ++r)
            ac[r] = fmaf(vmagg[(i0 + r) * DIM + l], wv, ac[r]);
    }
#pragma unroll
    for (int r = 0; r < 4; ++r) out[(i0 + r) * DIM + j] = ac[r];
}

extern "C" void kernel_launch(void* const* d_in, const int* in_sizes, int n_in,
                              void* d_out, int out_size, void* d_ws, size_t ws_size,
                              hipStream_t stream) {
    const float* x     = (const float*)d_in[0];
    const float* edges = (const float*)d_in[1];
    const int*   eidx  = (const int*)d_in[2];
    const float* Wq    = (const float*)d_in[3];
    const float* Wk    = (const float*)d_in[4];
    const float* Wv    = (const float*)d_in[5];
    const float* Wek   = (const float*)d_in[6];
    const float* Wev   = (const float*)d_in[7];
    const float* Wexp  = (const float*)d_in[8];
    const float* Wsq   = (const float*)d_in[9];
    const float* bsq   = (const float*)d_in[10];
    const float* Wout  = (const float*)d_in[11];
    const float* bout  = (const float*)d_in[12];
    const float* temp  = (const float*)d_in[13];

    float* ws = (float*)d_ws;
    float* q       = ws;                                  // 3.2M floats
    float* k       = q + (long)N_NODES * DIM;             // 3.2M
    float* v       = k + (long)N_NODES * DIM;             // 3.2M
    float* attn16s = v + (long)N_NODES * DIM;             // 12.8M (sorted)
    float* vmagg   = attn16s + (long)NEDGE * EXP_HEADS;   // 3.2M region
    float* a8s     = q;  // aliases q+k (dead after edge_attn); 6.4M
    // stats + dsts alias the vmagg region (dead before agg_kernel writes it)
    float2*   stats  = (float2*)vmagg;                          // 800k float2 (1.6M floats)
    unsigned* dsts   = (unsigned*)(vmagg + 1600000L);           // 800k u32
    unsigned* perm    = (unsigned*)(vmagg + (long)N_NODES * DIM);  // 800k
    unsigned* iperm   = perm + NEDGE;                              // 800k
    unsigned* srcs    = iperm + NEDGE;                             // 800k
    unsigned* cnt     = srcs + NEDGE;                              // 50k
    unsigned* offsets = cnt + N_NODES;                             // 50001
    unsigned* cursor  = offsets + N_NODES + 1;                     // 50k

    hipMemsetAsync(cnt, 0, (size_t)N_NODES * sizeof(unsigned), stream);

    float* out1 = (float*)d_out;               // [N, 64]
    float* out2 = out1 + (long)N_NODES * DIM;  // [8, E]

    qkv_kernel<<<(N_NODES / 4 * DIM + 255) / 256, 256, 0, stream>>>(x, Wq, Wk, Wv, q, k, v);
    hist_kernel<<<(NEDGE + 255) / 256, 256, 0, stream>>>(eidx, cnt);
    scan_kernel<<<1, SCAN_T, 0, stream>>>(cnt, offsets, cursor);
    scatter_kernel<<<(NEDGE + 255) / 256, 256, 0, stream>>>(eidx, cursor, perm, iperm, srcs, dsts);
    edge_attn_kernel<<<EA_BLOCKS, 256, 0, stream>>>(edges, q, k, Wek, Wexp, temp,
                                                    perm, dsts, srcs, attn16s);
    stats_kernel<<<(N_NODES * EXP_HEADS + 255) / 256, 256, 0, stream>>>(attn16s, offsets, stats);
    a8_kernel<<<NEDGE / 16, 256, 0, stream>>>(attn16s, dsts, stats, Wsq, bsq, a8s);
    agg_kernel<<<N_NODES / 4, 256, 0, stream>>>(edges, v, a8s, offsets, perm, srcs, Wev, vmagg);
    transpose_kernel<<<(NEDGE + 255) / 256, 256, 0, stream>>>(a8s, iperm, out2);
    out_kernel<<<(N_NODES / 4 * DIM + 255) / 256, 256, 0, stream>>>(vmagg, Wout, bout, out1);
}